// Round 1
// baseline (5385.336 us; speedup 1.0000x reference)
//
#include <hip/hip_runtime.h>
#include <stdint.h>

#define B_DIM 2048
#define C_DIM 1024
#define HW_SZ 49
#define M_DIM 65536
#define TOPK 32
#define EPS_F 1e-12f

typedef __attribute__((ext_vector_type(8))) __bf16 bf16x8;
typedef __attribute__((ext_vector_type(4))) float f32x4;
typedef __attribute__((ext_vector_type(4))) unsigned int u32x4;

static __device__ __forceinline__ unsigned short f2bf(float f) {
  uint32_t u = __builtin_bit_cast(uint32_t, f);
  u += 0x7FFFu + ((u >> 16) & 1u);
  return (unsigned short)(u >> 16);
}
static __device__ __forceinline__ float bf2f(unsigned short h) {
  uint32_t u = ((uint32_t)h) << 16;
  return __builtin_bit_cast(float, u);
}

// ---------------- q prep: spatial mean pool + L2 normalize + bf16 hi/lo split
__global__ __launch_bounds__(256) void prep_q(const float* __restrict__ q,
                                              unsigned short* __restrict__ qh,
                                              unsigned short* __restrict__ ql) {
  const int b = blockIdx.x;
  const int t = threadIdx.x;
  const float* base = q + (size_t)b * (C_DIM * HW_SZ);
  float qm[4];
  float ss = 0.f;
#pragma unroll
  for (int j = 0; j < 4; ++j) {
    const int c = t * 4 + j;
    const float* p = base + c * HW_SZ;
    float s = 0.f;
#pragma unroll
    for (int i = 0; i < 12; ++i) {
      float4 v = *reinterpret_cast<const float4*>(p + i * 4);
      s += v.x + v.y + v.z + v.w;
    }
    s += p[48];
    qm[j] = s * (1.0f / 49.0f);
    ss += qm[j] * qm[j];
  }
#pragma unroll
  for (int s_ = 32; s_; s_ >>= 1) ss += __shfl_xor(ss, s_);
  __shared__ float red[4];
  if ((t & 63) == 0) red[t >> 6] = ss;
  __syncthreads();
  const float tot = red[0] + red[1] + red[2] + red[3];
  const float scale = 1.0f / fmaxf(sqrtf(tot), EPS_F);
#pragma unroll
  for (int j = 0; j < 4; ++j) {
    const int c = t * 4 + j;
    const float qn = qm[j] * scale;
    const unsigned short hi = f2bf(qn);
    const float lo = qn - bf2f(hi);
    qh[(size_t)b * C_DIM + c] = hi;
    ql[(size_t)b * C_DIM + c] = f2bf(lo);
  }
}

// ---------------- key prep: L2 normalize + bf16 hi/lo split (1 wave per row)
__global__ __launch_bounds__(256) void prep_k(const float* __restrict__ keys,
                                              unsigned short* __restrict__ kh,
                                              unsigned short* __restrict__ kl) {
  const int t = threadIdx.x;
  const int lane = t & 63;
  const int row = blockIdx.x * 4 + (t >> 6);
  const float* p = keys + (size_t)row * C_DIM;
  float4 v[4];
  float ss = 0.f;
#pragma unroll
  for (int j = 0; j < 4; ++j) {
    v[j] = *reinterpret_cast<const float4*>(p + j * 256 + lane * 4);
    ss += v[j].x * v[j].x + v[j].y * v[j].y + v[j].z * v[j].z + v[j].w * v[j].w;
  }
#pragma unroll
  for (int s_ = 32; s_; s_ >>= 1) ss += __shfl_xor(ss, s_);
  const float scale = 1.0f / fmaxf(sqrtf(ss), EPS_F);
#pragma unroll
  for (int j = 0; j < 4; ++j) {
    float x[4] = {v[j].x * scale, v[j].y * scale, v[j].z * scale, v[j].w * scale};
    unsigned short hi[4], lo[4];
#pragma unroll
    for (int e = 0; e < 4; ++e) {
      hi[e] = f2bf(x[e]);
      lo[e] = f2bf(x[e] - bf2f(hi[e]));
    }
    const size_t off = (size_t)row * C_DIM + j * 256 + lane * 4;
    uint64_t hp, lp;
    memcpy(&hp, hi, 8); memcpy(&lp, lo, 8);
    *reinterpret_cast<uint64_t*>(kh + off) = hp;
    *reinterpret_cast<uint64_t*>(kl + off) = lp;
  }
}

// ---------------- sim GEMM: [2048 x 65536] = qn * kn^T, split-bf16 K=3072
// 128x128 tile, BK=64, 4 waves (2x2), global_load_lds staging, 16x16x32 MFMA
__global__ __launch_bounds__(256) void gemm_sim(
    const unsigned short* __restrict__ qh, const unsigned short* __restrict__ ql,
    const unsigned short* __restrict__ kh, const unsigned short* __restrict__ kl,
    float* __restrict__ sim) {
  __shared__ unsigned short lds_a[128 * 64];
  __shared__ unsigned short lds_b[128 * 64];
  const int t = threadIdx.x;
  const int lane = t & 63;
  const int w = t >> 6;
  const int wr = w >> 1, wc = w & 1;
  const int brow = blockIdx.x * 128;   // batch rows (M=2048, 16 tiles)
  const int bcol = blockIdx.y * 128;   // key rows  (N=65536, 512 tiles)
  const int fr = lane & 15;
  const int fk = (lane >> 4) * 8;
  f32x4 acc[4][4];
#pragma unroll
  for (int m = 0; m < 4; ++m)
#pragma unroll
    for (int n = 0; n < 4; ++n) acc[m][n] = f32x4{0.f, 0.f, 0.f, 0.f};

  for (int ks = 0; ks < 48; ++ks) {
    const int seg = ks >> 4;            // 0: hi*hi, 1: lo*hi, 2: hi*lo
    const int k0 = (ks & 15) * 64;      // col offset within the 1024-wide buffer
    const unsigned short* asrc = (seg == 1) ? ql : qh;
    const unsigned short* bsrc = (seg == 2) ? kl : kh;
#pragma unroll
    for (int i = 0; i < 4; ++i) {
      const int cb = i * 256 + w * 64;  // wave-uniform 16B-chunk base
      const int chunk = cb + lane;
      const int r = chunk >> 3;
      const int c8 = chunk & 7;
      __builtin_amdgcn_global_load_lds(
          (const __attribute__((address_space(1))) void*)(asrc + (size_t)(brow + r) * C_DIM + k0 + c8 * 8),
          (__attribute__((address_space(3))) void*)(lds_a + cb * 8), 16, 0, 0);
      __builtin_amdgcn_global_load_lds(
          (const __attribute__((address_space(1))) void*)(bsrc + (size_t)(bcol + r) * C_DIM + k0 + c8 * 8),
          (__attribute__((address_space(3))) void*)(lds_b + cb * 8), 16, 0, 0);
    }
    __syncthreads();  // compiler emits vmcnt(0) drain before barrier
#pragma unroll
    for (int kk = 0; kk < 2; ++kk) {
      bf16x8 af[4], bfv[4];
#pragma unroll
      for (int m = 0; m < 4; ++m) {
        u32x4 ua = *reinterpret_cast<const u32x4*>(lds_a + (wr * 64 + m * 16 + fr) * 64 + kk * 32 + fk);
        af[m] = __builtin_bit_cast(bf16x8, ua);
      }
#pragma unroll
      for (int n = 0; n < 4; ++n) {
        u32x4 ub = *reinterpret_cast<const u32x4*>(lds_b + (wc * 64 + n * 16 + fr) * 64 + kk * 32 + fk);
        bfv[n] = __builtin_bit_cast(bf16x8, ub);
      }
#pragma unroll
      for (int m = 0; m < 4; ++m)
#pragma unroll
        for (int n = 0; n < 4; ++n)
          acc[m][n] = __builtin_amdgcn_mfma_f32_16x16x32_bf16(af[m], bfv[n], acc[m][n], 0, 0, 0);
    }
    __syncthreads();
  }
  // epilogue: C/D layout col=lane&15, row=(lane>>4)*4+reg  [m89]
  const int orow0 = brow + wr * 64 + (lane >> 4) * 4;
  const int ocol0 = bcol + wc * 64 + (lane & 15);
#pragma unroll
  for (int m = 0; m < 4; ++m)
#pragma unroll
    for (int n = 0; n < 4; ++n)
#pragma unroll
      for (int j = 0; j < 4; ++j)
        sim[(size_t)(orow0 + m * 16 + j) * M_DIM + (ocol0 + n * 16)] = acc[m][n][j];
}

// ---------------- top-32 + softmax + gather+weighted sum (1 block per batch row)
__global__ __launch_bounds__(256) void topk_gather(
    const float* __restrict__ sim, const float* __restrict__ values,
    float* __restrict__ out) {
  const int b = blockIdx.x;
  const int t = threadIdx.x;
  const int lane = t & 63;
  const int w = t >> 6;
  __shared__ float lv[256 * 33];   // per-thread sorted lists, stride 33 = no bank conflict
  __shared__ int   li[256 * 33];
  __shared__ float topv[TOPK];
  __shared__ int   topi[TOPK];
  __shared__ float wv[4];
  __shared__ int   wt[4];
  __shared__ int   sel;
  __shared__ float wts[TOPK];
  float* myv = &lv[t * 33];
  int*   myi = &li[t * 33];
  const float* row = sim + (size_t)b * M_DIM;

  // phase 1: per-thread top-32 of its 256 strided values (insertion, early reject)
  int cnt = 0;
  float vmin = -INFINITY;
  for (int i = 0; i < 256; ++i) {
    const float v = row[t + (i << 8)];
    if (cnt == 32 && v <= vmin) continue;
    int j;
    if (cnt < 32) { j = cnt; ++cnt; } else { j = 31; }
    while (j > 0 && myv[j - 1] < v) { myv[j] = myv[j - 1]; myi[j] = myi[j - 1]; --j; }
    myv[j] = v;
    myi[j] = t + (i << 8);
    if (cnt == 32) vmin = myv[31];
  }
  __syncthreads();

  // phase 2: 32 rounds of block-wide argmax over the 256 list heads
  int ptr = 0;
  for (int r = 0; r < TOPK; ++r) {
    float v = (ptr < cnt) ? myv[ptr] : -INFINITY;
    int who = t;
#pragma unroll
    for (int s_ = 32; s_; s_ >>= 1) {
      const float ov = __shfl_xor(v, s_);
      const int   ow = __shfl_xor(who, s_);
      if (ov > v) { v = ov; who = ow; }
    }
    if (lane == 0) { wv[w] = v; wt[w] = who; }
    __syncthreads();
    if (t == 0) {
      float bv = wv[0]; int bt = wt[0];
#pragma unroll
      for (int i2 = 1; i2 < 4; ++i2)
        if (wv[i2] > bv) { bv = wv[i2]; bt = wt[i2]; }
      topv[r] = bv;
      sel = bt;
    }
    __syncthreads();
    if (t == sel) { topi[r] = myi[ptr]; ++ptr; }
  }
  __syncthreads();

  // softmax over top-32 (topv sorted descending, topv[0] = max)
  if (t < TOPK) wts[t] = expf(topv[t] - topv[0]);
  __syncthreads();
  float ssum = 0.f;
#pragma unroll
  for (int r = 0; r < TOPK; ++r) ssum += wts[r];
  const float inv = 1.0f / ssum;

  // gather: each thread owns 4 channels
  const int c0 = t * 4;
  float4 accv = make_float4(0.f, 0.f, 0.f, 0.f);
  for (int r = 0; r < TOPK; ++r) {
    const float4 vv = *reinterpret_cast<const float4*>(values + (size_t)topi[r] * C_DIM + c0);
    const float wgt = wts[r] * inv;
    accv.x += wgt * vv.x; accv.y += wgt * vv.y; accv.z += wgt * vv.z; accv.w += wgt * vv.w;
  }
  *reinterpret_cast<float4*>(out + (size_t)b * C_DIM + c0) = accv;
}

extern "C" void kernel_launch(void* const* d_in, const int* in_sizes, int n_in,
                              void* d_out, int out_size, void* d_ws, size_t ws_size,
                              hipStream_t stream) {
  const float* q      = (const float*)d_in[0];
  const float* keys   = (const float*)d_in[1];
  const float* values = (const float*)d_in[2];
  float* out = (float*)d_out;
  char* ws = (char*)d_ws;

  // workspace layout (bytes):
  //   kh : 65536*1024*2 = 134217728
  //   kl : 134217728
  //   qh : 2048*1024*2  = 4194304
  //   ql : 4194304
  //   sim: 2048*65536*4 = 536870912   -> total 813694976
  unsigned short* kh = (unsigned short*)(ws);
  unsigned short* kl = (unsigned short*)(ws + 134217728u);
  unsigned short* qh = (unsigned short*)(ws + 268435456u);
  unsigned short* ql = (unsigned short*)(ws + 272629760u);
  float* sim = (float*)(ws + 276824064u);

  hipLaunchKernelGGL(prep_q, dim3(B_DIM), dim3(256), 0, stream, q, qh, ql);
  hipLaunchKernelGGL(prep_k, dim3(M_DIM / 4), dim3(256), 0, stream, keys, kh, kl);
  hipLaunchKernelGGL(gemm_sim, dim3(B_DIM / 128, M_DIM / 128), dim3(256), 0, stream,
                     qh, ql, kh, kl, sim);
  hipLaunchKernelGGL(topk_gather, dim3(B_DIM), dim3(256), 0, stream, sim, values, out);
}